// Round 3
// baseline (1554.127 us; speedup 1.0000x reference)
//
#include <hip/hip_runtime.h>

typedef __attribute__((ext_vector_type(4))) float fx4;
typedef __attribute__((ext_vector_type(8))) unsigned short u16x8;
typedef __attribute__((ext_vector_type(8))) __bf16 bf16x8;

static __device__ __forceinline__ unsigned short f2bf(float f) {
  unsigned int u = __builtin_bit_cast(unsigned int, f);
  u += 0x7fffu + ((u >> 16) & 1u);          // round-to-nearest-even
  return (unsigned short)(u >> 16);
}
static __device__ __forceinline__ float bf2f(unsigned short s) {
  unsigned int u = ((unsigned int)s) << 16;
  return __builtin_bit_cast(float, u);
}
static __device__ __forceinline__ fx4 mfma16(u16x8 a, u16x8 b, fx4 c) {
  return __builtin_amdgcn_mfma_f32_16x16x32_bf16(
      __builtin_bit_cast(bf16x8, a), __builtin_bit_cast(bf16x8, b), c, 0, 0, 0);
}

// XOR swizzles (16B-block granular) for LDS tiles.
static __device__ __forceinline__ int swz128(int row, int col) {  // [16][128] bf16
  return row * 128 + (col ^ ((row & 7) << 3));
}
static __device__ __forceinline__ int swz32(int row, int col) {   // [16][32] bf16
  return row * 32 + (col ^ (((row >> 1) & 3) << 3));
}

// ---- ws layout (ushort units): weights bf16, transposed to [N][Kpad] ----
#define WT_FE1 0        // [128][32]  (fe_W1, K=18 pad 32)
#define WT_FE2 4096     // [128][128] (fe_W2)
#define WT_EE1 20480    // [128][32]  (ee_W1, K=4 pad 32)
#define WT_EE2 24576    // [128][128] (ee_W2)
#define WT_A   40960    // [128][128] (ie_W1 rows 0..127   : sr_sum)
#define WT_B   57344    // [128][128] (ie_W1 rows 128..255 : node_sum)
#define WT_C   73728    // [128][128] (ie_W1 rows 256..383 : edge_latent)
#define WT_IE2 90112    // [128][128] (ie_W2)
#define WT_TOTAL 106496

__global__ void prep_weights(const float* __restrict__ feW1, const float* __restrict__ feW2,
                             const float* __restrict__ eeW1, const float* __restrict__ eeW2,
                             const float* __restrict__ ieW1, const float* __restrict__ ieW2,
                             unsigned short* __restrict__ wt) {
  int i = blockIdx.x * 256 + threadIdx.x;
  if (i >= WT_TOTAL) return;
  unsigned short v;
  if (i < WT_FE2)      { int n = i >> 5, k = i & 31; v = (k < 18) ? f2bf(feW1[k * 128 + n]) : 0; }
  else if (i < WT_EE1) { int j = i - WT_FE2; int n = j >> 7, k = j & 127; v = f2bf(feW2[k * 128 + n]); }
  else if (i < WT_EE2) { int j = i - WT_EE1; int n = j >> 5, k = j & 31; v = (k < 4) ? f2bf(eeW1[k * 128 + n]) : 0; }
  else if (i < WT_A)   { int j = i - WT_EE2; int n = j >> 7, k = j & 127; v = f2bf(eeW2[k * 128 + n]); }
  else if (i < WT_B)   { int j = i - WT_A;   int n = j >> 7, k = j & 127; v = f2bf(ieW1[k * 128 + n]); }
  else if (i < WT_C)   { int j = i - WT_B;   int n = j >> 7, k = j & 127; v = f2bf(ieW1[(128 + k) * 128 + n]); }
  else if (i < WT_IE2) { int j = i - WT_C;   int n = j >> 7, k = j & 127; v = f2bf(ieW1[(256 + k) * 128 + n]); }
  else                 { int j = i - WT_IE2; int n = j >> 7, k = j & 127; v = f2bf(ieW2[k * 128 + n]); }
  wt[i] = v;
}

struct Params {
  const int* eidx;
  const float* dx; const float* attr;
  const float* basis[3];
  const float* sv[6]; const float* rv[6];
  const float* nl;
  const float* fe_b1; const float* fe_b2; const float* fe_g; const float* fe_be;
  const float* ee_b1; const float* ee_b2; const float* ee_g; const float* ee_be;
  const float* ie_b1; const float* ie_b2; const float* ie_g; const float* ie_be;
  const unsigned short* wt;
  float* out;
  int E;
};

// 16-row GEMM: A = wave-local LDS slice ([16][KPAD] swizzled bf16), B = global
// bf16 weights [128][KPAD]. acc[8] covers 16 rows x 128 cols.
template<int KPAD, int KT>
static __device__ __forceinline__ void gemm16(const unsigned short* As,
                                              const unsigned short* __restrict__ Bg,
                                              fx4* acc, int l16, int lgr) {
#pragma unroll
  for (int kk = 0; kk < KT; kk++) {
    const int k0 = kk * 32 + lgr * 8;
    const int idx = (KPAD == 32) ? swz32(l16, k0) : swz128(l16, k0);
    u16x8 af = *(const u16x8*)(As + idx);
#pragma unroll
    for (int nt = 0; nt < 8; nt++) {
      u16x8 bf = *(const u16x8*)(Bg + (nt * 16 + l16) * KPAD + k0);
      acc[nt] = mfma16(af, bf, acc[nt]);
    }
  }
}

// node_sum GEMM: A-fragments built directly from gathered node_latent rows.
static __device__ __forceinline__ void gemm_node(const float* __restrict__ nl,
                                                 int sidx, int ridx,
                                                 const unsigned short* __restrict__ Bg,
                                                 fx4* acc, int l16, int lgr) {
  const float* ns = nl + (size_t)sidx * 128;
  const float* nr = nl + (size_t)ridx * 128;
#pragma unroll
  for (int kk = 0; kk < 4; kk++) {
    const int k0 = kk * 32 + lgr * 8;
    fx4 a0 = *(const fx4*)(ns + k0), a1 = *(const fx4*)(ns + k0 + 4);
    fx4 b0 = *(const fx4*)(nr + k0), b1 = *(const fx4*)(nr + k0 + 4);
    u16x8 af;
#pragma unroll
    for (int j = 0; j < 4; j++) { af[j] = f2bf(a0[j] + b0[j]); af[4 + j] = f2bf(a1[j] + b1[j]); }
#pragma unroll
    for (int nt = 0; nt < 8; nt++) {
      u16x8 bf = *(const u16x8*)(Bg + (nt * 16 + l16) * 128 + k0);
      acc[nt] = mfma16(af, bf, acc[nt]);
    }
  }
}

// bias + ReLU -> bf16 store into wave-local [16][128] slice.
static __device__ __forceinline__ void relu_store(fx4* acc, const float* __restrict__ bias,
                                                  unsigned short* dst, int l16, int lgr) {
#pragma unroll
  for (int nt = 0; nt < 8; nt++) {
    const int col = nt * 16 + l16;
    const float b = bias[col];
#pragma unroll
    for (int r = 0; r < 4; r++) {
      float v = acc[nt][r] + b;
      dst[swz128(lgr * 4 + r, col)] = f2bf(v > 0.f ? v : 0.f);
    }
  }
}

// bias add + per-row LayerNorm (normalize only; caller applies g/beta).
static __device__ __forceinline__ void ln_rows(fx4* acc, const float* __restrict__ bias, int l16) {
  float sum[4] = {0, 0, 0, 0}, sq[4] = {0, 0, 0, 0};
#pragma unroll
  for (int nt = 0; nt < 8; nt++) {
    const float b = bias[nt * 16 + l16];
#pragma unroll
    for (int r = 0; r < 4; r++) {
      float v = acc[nt][r] + b; acc[nt][r] = v;
      sum[r] += v; sq[r] += v * v;
    }
  }
#pragma unroll
  for (int r = 0; r < 4; r++) {
    float s_ = sum[r], q_ = sq[r];
    for (int m = 1; m < 16; m <<= 1) { s_ += __shfl_xor(s_, m, 64); q_ += __shfl_xor(q_, m, 64); }
    const float mu = s_ * (1.f / 128.f);
    const float rs = rsqrtf(q_ * (1.f / 128.f) - mu * mu + 1e-5f);
#pragma unroll
    for (int nt = 0; nt < 8; nt++) acc[nt][r] = (acc[nt][r] - mu) * rs;
  }
}

// Per-wave arena: h1[0,2048) el[2048,4096) sr[4096,6144) feat[6144,6656)  (ushorts)
#define ARENA 6656

__global__ __launch_bounds__(256, 3) void fused(Params p) {
  __shared__ unsigned short lds[4 * ARENA];   // 53248 B -> 3 blocks/CU
  const int tid = threadIdx.x;
  const int wave = tid >> 6, lane = tid & 63;
  const int l16 = lane & 15, lgr = lane >> 4;
  unsigned short* const A = lds + wave * ARENA;
  unsigned short* const h1 = A;
  unsigned short* const el = A + 2048;
  unsigned short* const sr = A + 4096;
  unsigned short* const feat = A + 6144;
  const int e0w = blockIdx.x * 64 + wave * 16;
  const int e = e0w + l16;                    // this lane's edge (row = l16)
  const fx4 z4 = {0.f, 0.f, 0.f, 0.f};

  // hoist node indices early (used in phase 4)
  const int sidx = p.eidx[e];
  const int ridx = p.eidx[p.E + e];

  // ---------- Phase 1: ee MLP -> edge_latent ----------
  {
    // ee features: col0 = |dx|, col1..3 = attr; cols 4..31 zero (zeros at 18..31
    // are also relied upon by the fe phases below).
    if (lgr == 0) {
      float d0 = p.dx[3 * (size_t)e], d1 = p.dx[3 * (size_t)e + 1], d2 = p.dx[3 * (size_t)e + 2];
      feat[swz32(l16, 0)] = f2bf(sqrtf(d0 * d0 + d1 * d1 + d2 * d2));
    } else {
      feat[swz32(l16, lgr)] = f2bf(p.attr[3 * (size_t)e + (lgr - 1)]);
    }
#pragma unroll
    for (int j = 0; j < 7; j++) feat[swz32(l16, 4 + lgr * 7 + j)] = 0;

    fx4 acc[8];
#pragma unroll
    for (int b = 0; b < 8; b++) acc[b] = z4;
    gemm16<32, 1>(feat, p.wt + WT_EE1, acc, l16, lgr);
    relu_store(acc, p.ee_b1, h1, l16, lgr);
#pragma unroll
    for (int b = 0; b < 8; b++) acc[b] = z4;
    gemm16<128, 4>(h1, p.wt + WT_EE2, acc, l16, lgr);
    ln_rows(acc, p.ee_b2, l16);
#pragma unroll
    for (int nt = 0; nt < 8; nt++) {
      const int col = nt * 16 + l16;
      const float gg = p.ee_g[col], bb = p.ee_be[col];
#pragma unroll
      for (int r = 0; r < 4; r++)
        el[swz128(lgr * 4 + r, col)] = f2bf(acc[nt][r] * gg + bb);
    }
  }

  // ---------- Phase 2+3: fe MLP on senders then receivers -> sr_sum ----------
  fx4 latS[8];
  float bx[3][3];
#pragma unroll
  for (int i = 0; i < 3; i++) {
    const float* bp = p.basis[i] + 3 * (size_t)e;
    bx[i][0] = bp[0]; bx[i][1] = bp[1]; bx[i][2] = bp[2];
  }
#pragma unroll
  for (int side = 0; side < 2; side++) {
    const bool isR = (side == 1);
    // features: 6 projected vectors x 3 comps (cols 0..17); 18..31 already zero.
    // Compile-time k (rule #20: no runtime indexing of the pointer tables);
    // lane-group lgr handles k with (k & 3) == lgr -> exec-masked, SGPR pointers.
#pragma unroll
    for (int k = 0; k < 6; k++) {
      if ((k & 3) == lgr) {
        const float* vp = (isR ? p.rv[k] : p.sv[k]) + 3 * (size_t)e;
        const float v0 = vp[0], v1 = vp[1], v2 = vp[2];
        const float sgn = (isR && k != 3 && k != 5) ? -1.f : 1.f;
#pragma unroll
        for (int i = 0; i < 3; i++) {
          float d = (bx[i][0] * v0 + bx[i][1] * v1 + bx[i][2] * v2) * sgn;
          feat[swz32(l16, k * 3 + i)] = f2bf(d);
        }
      }
    }

    fx4 acc[8];
#pragma unroll
    for (int b = 0; b < 8; b++) acc[b] = z4;
    gemm16<32, 1>(feat, p.wt + WT_FE1, acc, l16, lgr);
    relu_store(acc, p.fe_b1, h1, l16, lgr);
#pragma unroll
    for (int b = 0; b < 8; b++) acc[b] = z4;
    gemm16<128, 4>(h1, p.wt + WT_FE2, acc, l16, lgr);
    ln_rows(acc, p.fe_b2, l16);
    if (!isR) {
#pragma unroll
      for (int nt = 0; nt < 8; nt++) {
        const int col = nt * 16 + l16;
        const float gg = p.fe_g[col], bb = p.fe_be[col];
#pragma unroll
        for (int r = 0; r < 4; r++) latS[nt][r] = acc[nt][r] * gg + bb;
      }
    } else {
#pragma unroll
      for (int nt = 0; nt < 8; nt++) {
        const int col = nt * 16 + l16;
        const float gg = p.fe_g[col], bb = p.fe_be[col];
#pragma unroll
        for (int r = 0; r < 4; r++)
          sr[swz128(lgr * 4 + r, col)] = f2bf(latS[nt][r] + acc[nt][r] * gg + bb);
      }
    }
  }

  // ---------- Phase 4: ie layer1 = sr-GEMM + el-GEMM + node-GEMM, ReLU ----------
  {
    fx4 acc[8];
#pragma unroll
    for (int b = 0; b < 8; b++) acc[b] = z4;
    gemm_node(p.nl, sidx, ridx, p.wt + WT_B, acc, l16, lgr);   // issue gathers first
    gemm16<128, 4>(sr, p.wt + WT_A, acc, l16, lgr);
    gemm16<128, 4>(el, p.wt + WT_C, acc, l16, lgr);
    relu_store(acc, p.ie_b1, h1, l16, lgr);
  }

  // ---------- Phase 5: ie layer2 + LN -> out ----------
  {
    fx4 acc[8];
#pragma unroll
    for (int b = 0; b < 8; b++) acc[b] = z4;
    gemm16<128, 4>(h1, p.wt + WT_IE2, acc, l16, lgr);
    ln_rows(acc, p.ie_b2, l16);
#pragma unroll
    for (int nt = 0; nt < 8; nt++) {
      const int col = nt * 16 + l16;
      const float gg = p.ie_g[col], bb = p.ie_be[col];
#pragma unroll
      for (int r = 0; r < 4; r++)
        p.out[(size_t)(e0w + lgr * 4 + r) * 128 + col] = acc[nt][r] * gg + bb;
    }
  }
}

extern "C" void kernel_launch(void* const* d_in, const int* in_sizes, int n_in,
                              void* d_out, int out_size, void* d_ws, size_t ws_size,
                              hipStream_t stream) {
  (void)n_in; (void)out_size;
  const int E = in_sizes[1] / 3;  // edge_dx_ is [E,3]
  unsigned short* wt = reinterpret_cast<unsigned short*>(d_ws);
  if (ws_size < (size_t)WT_TOTAL * sizeof(unsigned short)) return;

  prep_weights<<<(WT_TOTAL + 255) / 256, 256, 0, stream>>>(
      (const float*)d_in[19], (const float*)d_in[21],
      (const float*)d_in[25], (const float*)d_in[27],
      (const float*)d_in[31], (const float*)d_in[33], wt);

  Params p;
  p.eidx = (const int*)d_in[0];
  p.dx = (const float*)d_in[1];
  p.attr = (const float*)d_in[2];
  for (int i = 0; i < 3; i++) p.basis[i] = (const float*)d_in[3 + i];
  for (int k = 0; k < 6; k++) { p.sv[k] = (const float*)d_in[6 + k]; p.rv[k] = (const float*)d_in[12 + k]; }
  p.nl = (const float*)d_in[18];
  p.fe_b1 = (const float*)d_in[20]; p.fe_b2 = (const float*)d_in[22];
  p.fe_g  = (const float*)d_in[23]; p.fe_be = (const float*)d_in[24];
  p.ee_b1 = (const float*)d_in[26]; p.ee_b2 = (const float*)d_in[28];
  p.ee_g  = (const float*)d_in[29]; p.ee_be = (const float*)d_in[30];
  p.ie_b1 = (const float*)d_in[32]; p.ie_b2 = (const float*)d_in[34];
  p.ie_g  = (const float*)d_in[35]; p.ie_be = (const float*)d_in[36];
  p.wt = wt;
  p.out = (float*)d_out;
  p.E = E;
  fused<<<E / 64, 256, 0, stream>>>(p);
}

// Round 4
// 1498.881 us; speedup vs baseline: 1.0369x; 1.0369x over previous
//
#include <hip/hip_runtime.h>

typedef __attribute__((ext_vector_type(4))) float fx4;
typedef __attribute__((ext_vector_type(8))) unsigned short u16x8;
typedef __attribute__((ext_vector_type(8))) __bf16 bf16x8;

static __device__ __forceinline__ unsigned short f2bf(float f) {
  unsigned int u = __builtin_bit_cast(unsigned int, f);
  u += 0x7fffu + ((u >> 16) & 1u);          // round-to-nearest-even
  return (unsigned short)(u >> 16);
}
static __device__ __forceinline__ float bf2f(unsigned short s) {
  unsigned int u = ((unsigned int)s) << 16;
  return __builtin_bit_cast(float, u);
}
static __device__ __forceinline__ fx4 mfma16(u16x8 a, u16x8 b, fx4 c) {
  return __builtin_amdgcn_mfma_f32_16x16x32_bf16(
      __builtin_bit_cast(bf16x8, a), __builtin_bit_cast(bf16x8, b), c, 0, 0, 0);
}

// XOR swizzles (16B-block granular) for LDS tiles.
static __device__ __forceinline__ int swz128(int row, int col) {  // [16][128] bf16
  return row * 128 + (col ^ ((row & 7) << 3));
}
static __device__ __forceinline__ int swz32(int row, int col) {   // [16][32] bf16
  return row * 32 + (col ^ (((row >> 1) & 3) << 3));
}

// ---- ws layout (ushort units): weights bf16, transposed to [N][Kpad] ----
#define WT_FE1 0        // [128][32]  (fe_W1, K=18 pad 32)
#define WT_FE2 4096     // [128][128] (fe_W2)
#define WT_EE1 20480    // [128][32]  (ee_W1, K=4 pad 32)
#define WT_EE2 24576    // [128][128] (ee_W2)
#define WT_A   40960    // [128][128] (ie_W1 rows 0..127   : sr_sum)
#define WT_B   57344    // [128][128] (ie_W1 rows 128..255 : node_sum)
#define WT_C   73728    // [128][128] (ie_W1 rows 256..383 : edge_latent)
#define WT_IE2 90112    // [128][128] (ie_W2)
#define WT_TOTAL 106496

__global__ void prep_weights(const float* __restrict__ feW1, const float* __restrict__ feW2,
                             const float* __restrict__ eeW1, const float* __restrict__ eeW2,
                             const float* __restrict__ ieW1, const float* __restrict__ ieW2,
                             unsigned short* __restrict__ wt) {
  int i = blockIdx.x * 256 + threadIdx.x;
  if (i >= WT_TOTAL) return;
  unsigned short v;
  if (i < WT_FE2)      { int n = i >> 5, k = i & 31; v = (k < 18) ? f2bf(feW1[k * 128 + n]) : 0; }
  else if (i < WT_EE1) { int j = i - WT_FE2; int n = j >> 7, k = j & 127; v = f2bf(feW2[k * 128 + n]); }
  else if (i < WT_EE2) { int j = i - WT_EE1; int n = j >> 5, k = j & 31; v = (k < 4) ? f2bf(eeW1[k * 128 + n]) : 0; }
  else if (i < WT_A)   { int j = i - WT_EE2; int n = j >> 7, k = j & 127; v = f2bf(eeW2[k * 128 + n]); }
  else if (i < WT_B)   { int j = i - WT_A;   int n = j >> 7, k = j & 127; v = f2bf(ieW1[k * 128 + n]); }
  else if (i < WT_C)   { int j = i - WT_B;   int n = j >> 7, k = j & 127; v = f2bf(ieW1[(128 + k) * 128 + n]); }
  else if (i < WT_IE2) { int j = i - WT_C;   int n = j >> 7, k = j & 127; v = f2bf(ieW1[(256 + k) * 128 + n]); }
  else                 { int j = i - WT_IE2; int n = j >> 7, k = j & 127; v = f2bf(ieW2[k * 128 + n]); }
  wt[i] = v;
}

struct Params {
  const int* eidx;
  const float* dx; const float* attr;
  const float* basis[3];
  const float* sv[6]; const float* rv[6];
  const float* nl;
  const float* fe_b1; const float* fe_b2; const float* fe_g; const float* fe_be;
  const float* ee_b1; const float* ee_b2; const float* ee_g; const float* ee_be;
  const float* ie_b1; const float* ie_b2; const float* ie_g; const float* ie_be;
  const unsigned short* wt;
  float* out;
  int E;
};

// 16-row GEMM: A = wave-local LDS slice ([16][KPAD] swizzled bf16), B = global
// bf16 weights [128][KPAD]. acc[8] covers 16 rows x 128 cols.
template<int KPAD, int KT>
static __device__ __forceinline__ void gemm16(const unsigned short* As,
                                              const unsigned short* __restrict__ Bg,
                                              fx4* acc, int l16, int lgr) {
#pragma unroll
  for (int kk = 0; kk < KT; kk++) {
    const int k0 = kk * 32 + lgr * 8;
    const int idx = (KPAD == 32) ? swz32(l16, k0) : swz128(l16, k0);
    u16x8 af = *(const u16x8*)(As + idx);
#pragma unroll
    for (int nt = 0; nt < 8; nt++) {
      u16x8 bf = *(const u16x8*)(Bg + (nt * 16 + l16) * KPAD + k0);
      acc[nt] = mfma16(af, bf, acc[nt]);
    }
  }
}

// node_sum GEMM: A-fragments built directly from gathered node_latent rows.
static __device__ __forceinline__ void gemm_node(const float* __restrict__ nl,
                                                 int sidx, int ridx,
                                                 const unsigned short* __restrict__ Bg,
                                                 fx4* acc, int l16, int lgr) {
  const float* ns = nl + (size_t)sidx * 128;
  const float* nr = nl + (size_t)ridx * 128;
#pragma unroll
  for (int kk = 0; kk < 4; kk++) {
    const int k0 = kk * 32 + lgr * 8;
    fx4 a0 = *(const fx4*)(ns + k0), a1 = *(const fx4*)(ns + k0 + 4);
    fx4 b0 = *(const fx4*)(nr + k0), b1 = *(const fx4*)(nr + k0 + 4);
    u16x8 af;
#pragma unroll
    for (int j = 0; j < 4; j++) { af[j] = f2bf(a0[j] + b0[j]); af[4 + j] = f2bf(a1[j] + b1[j]); }
#pragma unroll
    for (int nt = 0; nt < 8; nt++) {
      u16x8 bf = *(const u16x8*)(Bg + (nt * 16 + l16) * 128 + k0);
      acc[nt] = mfma16(af, bf, acc[nt]);
    }
  }
}

// bias + ReLU -> bf16 store into wave-local [16][128] slice.
static __device__ __forceinline__ void relu_store(fx4* acc, const float* __restrict__ bias,
                                                  unsigned short* dst, int l16, int lgr) {
#pragma unroll
  for (int nt = 0; nt < 8; nt++) {
    const int col = nt * 16 + l16;
    const float b = bias[col];
#pragma unroll
    for (int r = 0; r < 4; r++) {
      float v = acc[nt][r] + b;
      dst[swz128(lgr * 4 + r, col)] = f2bf(v > 0.f ? v : 0.f);
    }
  }
}

// bias add + per-row LayerNorm (normalize only; caller applies g/beta).
static __device__ __forceinline__ void ln_rows(fx4* acc, const float* __restrict__ bias, int l16) {
  float sum[4] = {0, 0, 0, 0}, sq[4] = {0, 0, 0, 0};
#pragma unroll
  for (int nt = 0; nt < 8; nt++) {
    const float b = bias[nt * 16 + l16];
#pragma unroll
    for (int r = 0; r < 4; r++) {
      float v = acc[nt][r] + b; acc[nt][r] = v;
      sum[r] += v; sq[r] += v * v;
    }
  }
#pragma unroll
  for (int r = 0; r < 4; r++) {
    float s_ = sum[r], q_ = sq[r];
#pragma unroll
    for (int m = 1; m < 16; m <<= 1) { s_ += __shfl_xor(s_, m, 64); q_ += __shfl_xor(q_, m, 64); }
    const float mu = s_ * (1.f / 128.f);
    const float rs = rsqrtf(q_ * (1.f / 128.f) - mu * mu + 1e-5f);
#pragma unroll
    for (int nt = 0; nt < 8; nt++) acc[nt][r] = (acc[nt][r] - mu) * rs;
  }
}

// Per-wave arena: h1[0,2048) el[2048,4096) sr[4096,6144) feat[6144,6656)  (ushorts)
#define ARENA 6656

// NOTE: plain __launch_bounds__(256). Adding a min-waves/EU arg (256,3) made
// AMDGPUPromoteAlloca refuse to promote the fx4 acc/latS allocas (budget
// heuristic), leaving ~720 B/thread in scratch: VGPR=84, +2.8 GB HBM traffic.
__global__ __launch_bounds__(256) void fused(Params p) {
  __shared__ unsigned short lds[4 * ARENA];   // 53248 B -> 3 blocks/CU by LDS
  const int tid = threadIdx.x;
  const int wave = tid >> 6, lane = tid & 63;
  const int l16 = lane & 15, lgr = lane >> 4;
  unsigned short* const A = lds + wave * ARENA;
  unsigned short* const h1 = A;
  unsigned short* const el = A + 2048;
  unsigned short* const sr = A + 4096;
  unsigned short* const feat = A + 6144;
  const int e0w = blockIdx.x * 64 + wave * 16;
  const int e = e0w + l16;                    // this lane's edge (row = l16)
  const fx4 z4 = {0.f, 0.f, 0.f, 0.f};

  // hoist node indices early (used in phase 4)
  const int sidx = p.eidx[e];
  const int ridx = p.eidx[p.E + e];

  // ---------- Phase 1: ee MLP -> edge_latent ----------
  {
    // ee features: col0 = |dx|, col1..3 = attr; cols 4..31 zero (zeros at 18..31
    // are also relied upon by the fe phases below).
    if (lgr == 0) {
      float d0 = p.dx[3 * (size_t)e], d1 = p.dx[3 * (size_t)e + 1], d2 = p.dx[3 * (size_t)e + 2];
      feat[swz32(l16, 0)] = f2bf(sqrtf(d0 * d0 + d1 * d1 + d2 * d2));
    } else {
      feat[swz32(l16, lgr)] = f2bf(p.attr[3 * (size_t)e + (lgr - 1)]);
    }
#pragma unroll
    for (int j = 0; j < 7; j++) feat[swz32(l16, 4 + lgr * 7 + j)] = 0;

    fx4 acc[8];
#pragma unroll
    for (int b = 0; b < 8; b++) acc[b] = z4;
    gemm16<32, 1>(feat, p.wt + WT_EE1, acc, l16, lgr);
    relu_store(acc, p.ee_b1, h1, l16, lgr);
#pragma unroll
    for (int b = 0; b < 8; b++) acc[b] = z4;
    gemm16<128, 4>(h1, p.wt + WT_EE2, acc, l16, lgr);
    ln_rows(acc, p.ee_b2, l16);
#pragma unroll
    for (int nt = 0; nt < 8; nt++) {
      const int col = nt * 16 + l16;
      const float gg = p.ee_g[col], bb = p.ee_be[col];
#pragma unroll
      for (int r = 0; r < 4; r++)
        el[swz128(lgr * 4 + r, col)] = f2bf(acc[nt][r] * gg + bb);
    }
  }

  // ---------- Phase 2+3: fe MLP on senders then receivers -> sr_sum ----------
  fx4 latS[8];
  float bx[3][3];
#pragma unroll
  for (int i = 0; i < 3; i++) {
    const float* bp = p.basis[i] + 3 * (size_t)e;
    bx[i][0] = bp[0]; bx[i][1] = bp[1]; bx[i][2] = bp[2];
  }
#pragma unroll
  for (int side = 0; side < 2; side++) {
    const bool isR = (side == 1);
    // features: 6 projected vectors x 3 comps (cols 0..17); 18..31 already zero.
    // Compile-time k (rule #20: no runtime indexing of the pointer tables);
    // lane-group lgr handles k with (k & 3) == lgr -> exec-masked, SGPR pointers.
#pragma unroll
    for (int k = 0; k < 6; k++) {
      if ((k & 3) == lgr) {
        const float* vp = (isR ? p.rv[k] : p.sv[k]) + 3 * (size_t)e;
        const float v0 = vp[0], v1 = vp[1], v2 = vp[2];
        const float sgn = (isR && k != 3 && k != 5) ? -1.f : 1.f;
#pragma unroll
        for (int i = 0; i < 3; i++) {
          float d = (bx[i][0] * v0 + bx[i][1] * v1 + bx[i][2] * v2) * sgn;
          feat[swz32(l16, k * 3 + i)] = f2bf(d);
        }
      }
    }

    fx4 acc[8];
#pragma unroll
    for (int b = 0; b < 8; b++) acc[b] = z4;
    gemm16<32, 1>(feat, p.wt + WT_FE1, acc, l16, lgr);
    relu_store(acc, p.fe_b1, h1, l16, lgr);
#pragma unroll
    for (int b = 0; b < 8; b++) acc[b] = z4;
    gemm16<128, 4>(h1, p.wt + WT_FE2, acc, l16, lgr);
    ln_rows(acc, p.fe_b2, l16);
    if (!isR) {
#pragma unroll
      for (int nt = 0; nt < 8; nt++) {
        const int col = nt * 16 + l16;
        const float gg = p.fe_g[col], bb = p.fe_be[col];
#pragma unroll
        for (int r = 0; r < 4; r++) latS[nt][r] = acc[nt][r] * gg + bb;
      }
    } else {
#pragma unroll
      for (int nt = 0; nt < 8; nt++) {
        const int col = nt * 16 + l16;
        const float gg = p.fe_g[col], bb = p.fe_be[col];
#pragma unroll
        for (int r = 0; r < 4; r++)
          sr[swz128(lgr * 4 + r, col)] = f2bf(latS[nt][r] + acc[nt][r] * gg + bb);
      }
    }
  }

  // ---------- Phase 4: ie layer1 = sr-GEMM + el-GEMM + node-GEMM, ReLU ----------
  {
    fx4 acc[8];
#pragma unroll
    for (int b = 0; b < 8; b++) acc[b] = z4;
    gemm_node(p.nl, sidx, ridx, p.wt + WT_B, acc, l16, lgr);   // issue gathers first
    gemm16<128, 4>(sr, p.wt + WT_A, acc, l16, lgr);
    gemm16<128, 4>(el, p.wt + WT_C, acc, l16, lgr);
    relu_store(acc, p.ie_b1, h1, l16, lgr);
  }

  // ---------- Phase 5: ie layer2 + LN -> out ----------
  {
    fx4 acc[8];
#pragma unroll
    for (int b = 0; b < 8; b++) acc[b] = z4;
    gemm16<128, 4>(h1, p.wt + WT_IE2, acc, l16, lgr);
    ln_rows(acc, p.ie_b2, l16);
#pragma unroll
    for (int nt = 0; nt < 8; nt++) {
      const int col = nt * 16 + l16;
      const float gg = p.ie_g[col], bb = p.ie_be[col];
#pragma unroll
      for (int r = 0; r < 4; r++)
        p.out[(size_t)(e0w + lgr * 4 + r) * 128 + col] = acc[nt][r] * gg + bb;
    }
  }
}

extern "C" void kernel_launch(void* const* d_in, const int* in_sizes, int n_in,
                              void* d_out, int out_size, void* d_ws, size_t ws_size,
                              hipStream_t stream) {
  (void)n_in; (void)out_size;
  const int E = in_sizes[1] / 3;  // edge_dx_ is [E,3]
  unsigned short* wt = reinterpret_cast<unsigned short*>(d_ws);
  if (ws_size < (size_t)WT_TOTAL * sizeof(unsigned short)) return;

  prep_weights<<<(WT_TOTAL + 255) / 256, 256, 0, stream>>>(
      (const float*)d_in[19], (const float*)d_in[21],
      (const float*)d_in[25], (const float*)d_in[27],
      (const float*)d_in[31], (const float*)d_in[33], wt);

  Params p;
  p.eidx = (const int*)d_in[0];
  p.dx = (const float*)d_in[1];
  p.attr = (const float*)d_in[2];
  for (int i = 0; i < 3; i++) p.basis[i] = (const float*)d_in[3 + i];
  for (int k = 0; k < 6; k++) { p.sv[k] = (const float*)d_in[6 + k]; p.rv[k] = (const float*)d_in[12 + k]; }
  p.nl = (const float*)d_in[18];
  p.fe_b1 = (const float*)d_in[20]; p.fe_b2 = (const float*)d_in[22];
  p.fe_g  = (const float*)d_in[23]; p.fe_be = (const float*)d_in[24];
  p.ee_b1 = (const float*)d_in[26]; p.ee_b2 = (const float*)d_in[28];
  p.ee_g  = (const float*)d_in[29]; p.ee_be = (const float*)d_in[30];
  p.ie_b1 = (const float*)d_in[32]; p.ie_b2 = (const float*)d_in[34];
  p.ie_g  = (const float*)d_in[35]; p.ie_be = (const float*)d_in[36];
  p.wt = wt;
  p.out = (float*)d_out;
  p.E = E;
  fused<<<E / 64, 256, 0, stream>>>(p);
}

// Round 5
// 675.559 us; speedup vs baseline: 2.3005x; 2.2187x over previous
//
#include <hip/hip_runtime.h>

typedef __attribute__((ext_vector_type(4))) float fx4;
typedef __attribute__((ext_vector_type(8))) unsigned short u16x8;
typedef __attribute__((ext_vector_type(8))) __bf16 bf16x8;

static __device__ __forceinline__ unsigned short f2bf(float f) {
  unsigned int u = __builtin_bit_cast(unsigned int, f);
  u += 0x7fffu + ((u >> 16) & 1u);          // round-to-nearest-even
  return (unsigned short)(u >> 16);
}
static __device__ __forceinline__ fx4 mfma16(u16x8 a, u16x8 b, fx4 c) {
  return __builtin_amdgcn_mfma_f32_16x16x32_bf16(
      __builtin_bit_cast(bf16x8, a), __builtin_bit_cast(bf16x8, b), c, 0, 0, 0);
}

// XOR swizzles (16B-block granular). Weights are PRE-swizzled in ws by prep,
// so kernels copy them linearly into LDS and read with the same swizzle.
static __device__ __forceinline__ int swz128(int row, int col) {  // [.][128] bf16
  return row * 128 + (col ^ ((row & 7) << 3));
}
static __device__ __forceinline__ int swz32(int row, int col) {   // [.][32] bf16
  return row * 32 + (col ^ (((row >> 1) & 3) << 3));
}

// ---- ws layout (ushort units): weights bf16, [N][Kpad], pre-swizzled ----
#define WT_FE1 0        // [128][32]  (fe_W1, K=18 pad 32)
#define WT_FE2 4096     // [128][128] (fe_W2)
#define WT_EE1 20480    // [128][32]  (ee_W1, K=4 pad 32)
#define WT_EE2 24576    // [128][128] (ee_W2)
#define WT_A   40960    // [128][128] (ie_W1 rows 0..127   : sr_sum)
#define WT_B   57344    // [128][128] (ie_W1 rows 128..255 : node_sum)
#define WT_C   73728    // [128][128] (ie_W1 rows 256..383 : edge_latent)
#define WT_IE2 90112    // [128][128] (ie_W2)
#define WT_TOTAL 106496

__global__ void prep_weights(const float* __restrict__ feW1, const float* __restrict__ feW2,
                             const float* __restrict__ eeW1, const float* __restrict__ eeW2,
                             const float* __restrict__ ieW1, const float* __restrict__ ieW2,
                             unsigned short* __restrict__ wt) {
  int i = blockIdx.x * 256 + threadIdx.x;
  if (i >= WT_TOTAL) return;
  int base, n, k, kpad;
  float val;
  if (i < WT_FE2)      { base = WT_FE1; n = i >> 5; k = i & 31; kpad = 32;
                         val = (k < 18) ? feW1[k * 128 + n] : 0.f; }
  else if (i < WT_EE1) { base = WT_FE2; int j = i - WT_FE2; n = j >> 7; k = j & 127; kpad = 128;
                         val = feW2[k * 128 + n]; }
  else if (i < WT_EE2) { base = WT_EE1; int j = i - WT_EE1; n = j >> 5; k = j & 31; kpad = 32;
                         val = (k < 4) ? eeW1[k * 128 + n] : 0.f; }
  else if (i < WT_A)   { base = WT_EE2; int j = i - WT_EE2; n = j >> 7; k = j & 127; kpad = 128;
                         val = eeW2[k * 128 + n]; }
  else if (i < WT_B)   { base = WT_A;   int j = i - WT_A;   n = j >> 7; k = j & 127; kpad = 128;
                         val = ieW1[k * 128 + n]; }
  else if (i < WT_C)   { base = WT_B;   int j = i - WT_B;   n = j >> 7; k = j & 127; kpad = 128;
                         val = ieW1[(128 + k) * 128 + n]; }
  else if (i < WT_IE2) { base = WT_C;   int j = i - WT_C;   n = j >> 7; k = j & 127; kpad = 128;
                         val = ieW1[(256 + k) * 128 + n]; }
  else                 { base = WT_IE2; int j = i - WT_IE2; n = j >> 7; k = j & 127; kpad = 128;
                         val = ieW2[k * 128 + n]; }
  int dst = (kpad == 32) ? base + n * 32 + (k ^ (((n >> 1) & 3) << 3))
                         : base + n * 128 + (k ^ ((n & 7) << 3));
  wt[dst] = f2bf(val);
}

// 16-row GEMM, A from wave-local LDS arena, B from LDS weights (both swizzled).
template<int KPAD, int KT>
static __device__ __forceinline__ void gemm_lds(const unsigned short* As,
                                                const unsigned short* Ws,
                                                fx4* acc, int l16, int lgr) {
#pragma unroll
  for (int kk = 0; kk < KT; kk++) {
    const int k0 = kk * 32 + lgr * 8;
    u16x8 af = *(const u16x8*)(As + ((KPAD == 32) ? swz32(l16, k0) : swz128(l16, k0)));
#pragma unroll
    for (int nt = 0; nt < 8; nt++) {
      const int n = nt * 16 + l16;
      u16x8 bf = *(const u16x8*)(Ws + ((KPAD == 32) ? swz32(n, k0) : swz128(n, k0)));
      acc[nt] = mfma16(af, bf, acc[nt]);
    }
  }
}

// bias + ReLU -> bf16 store into wave-local [16][128] slice.
static __device__ __forceinline__ void relu_store(fx4* acc, const float* __restrict__ bias,
                                                  unsigned short* dst, int l16, int lgr) {
#pragma unroll
  for (int nt = 0; nt < 8; nt++) {
    const int col = nt * 16 + l16;
    const float b = bias[col];
#pragma unroll
    for (int r = 0; r < 4; r++) {
      float v = acc[nt][r] + b;
      dst[swz128(lgr * 4 + r, col)] = f2bf(v > 0.f ? v : 0.f);
    }
  }
}

// bias add + per-row LayerNorm (normalize only; caller applies g/beta).
static __device__ __forceinline__ void ln_rows(fx4* acc, const float* __restrict__ bias, int l16) {
  float sum[4] = {0, 0, 0, 0}, sq[4] = {0, 0, 0, 0};
#pragma unroll
  for (int nt = 0; nt < 8; nt++) {
    const float b = bias[nt * 16 + l16];
#pragma unroll
    for (int r = 0; r < 4; r++) {
      float v = acc[nt][r] + b; acc[nt][r] = v;
      sum[r] += v; sq[r] += v * v;
    }
  }
#pragma unroll
  for (int r = 0; r < 4; r++) {
    float s_ = sum[r], q_ = sq[r];
#pragma unroll
    for (int m = 1; m < 16; m <<= 1) { s_ += __shfl_xor(s_, m, 64); q_ += __shfl_xor(q_, m, 64); }
    const float mu = s_ * (1.f / 128.f);
    const float rs = rsqrtf(q_ * (1.f / 128.f) - mu * mu + 1e-5f);
#pragma unroll
    for (int nt = 0; nt < 8; nt++) acc[nt][r] = (acc[nt][r] - mu) * rs;
  }
}

// ======================= fe kernel (senders/receivers MLP) =======================
struct ParamsFE {
  const float* basis[3];
  const float* sv[6]; const float* rv[6];
  const float* b1; const float* b2; const float* g; const float* be;
  const unsigned short* wt;
  unsigned short* msg;   // [E][256] bf16, cols 0..127 = sr_sum (aliases d_out)
  int ntiles;
};

__global__ __launch_bounds__(256) void fe_kernel(ParamsFE p) {
  __shared__ unsigned short lds[30720];  // W1 4096 | W2 16384 | 4 x (h1 2048 + feat 512)
  const int tid = threadIdx.x;
  const int wave = tid >> 6, lane = tid & 63;
  const int l16 = lane & 15, lgr = lane >> 4;
#pragma unroll
  for (int i = tid * 8; i < 20480; i += 2048)
    *(u16x8*)(lds + i) = *(const u16x8*)(p.wt + WT_FE1 + i);
  const unsigned short* W1 = lds;
  const unsigned short* W2 = lds + 4096;
  unsigned short* h1 = lds + 20480 + wave * 2560;
  unsigned short* feat = h1 + 2048;
  __syncthreads();
  // persistent zeros in feat cols 18..31 (never overwritten)
#pragma unroll
  for (int j = 0; j < 4; j++) { int c = 18 + lgr * 4 + j; if (c < 32) feat[swz32(l16, c)] = 0; }
  const fx4 z4 = {0.f, 0.f, 0.f, 0.f};

  for (int t = blockIdx.x; t < p.ntiles; t += gridDim.x) {
    const int e0 = t * 64 + wave * 16;
    const size_t e = (size_t)(e0 + l16);
    float bx[3][3];
#pragma unroll
    for (int i = 0; i < 3; i++) {
      const float* bp = p.basis[i] + 3 * e;
      bx[i][0] = bp[0]; bx[i][1] = bp[1]; bx[i][2] = bp[2];
    }
    fx4 latS[8];
#pragma unroll
    for (int side = 0; side < 2; side++) {
      const bool isR = (side == 1);
#pragma unroll
      for (int k = 0; k < 6; k++) {
        if ((k & 3) == lgr) {   // compile-time k; exec-masked lanes
          const float* vp = (isR ? p.rv[k] : p.sv[k]) + 3 * e;
          const float v0 = vp[0], v1 = vp[1], v2 = vp[2];
          const float sgn = (isR && k != 3 && k != 5) ? -1.f : 1.f;
#pragma unroll
          for (int i = 0; i < 3; i++) {
            float d = (bx[i][0] * v0 + bx[i][1] * v1 + bx[i][2] * v2) * sgn;
            feat[swz32(l16, k * 3 + i)] = f2bf(d);
          }
        }
      }
      fx4 acc[8];
#pragma unroll
      for (int b = 0; b < 8; b++) acc[b] = z4;
      gemm_lds<32, 1>(feat, W1, acc, l16, lgr);
      relu_store(acc, p.b1, h1, l16, lgr);
#pragma unroll
      for (int b = 0; b < 8; b++) acc[b] = z4;
      gemm_lds<128, 4>(h1, W2, acc, l16, lgr);
      ln_rows(acc, p.b2, l16);
      if (!isR) {
#pragma unroll
        for (int nt = 0; nt < 8; nt++) {
          const int col = nt * 16 + l16;
          const float gg = p.g[col], bb = p.be[col];
#pragma unroll
          for (int r = 0; r < 4; r++) latS[nt][r] = acc[nt][r] * gg + bb;
        }
      } else {
#pragma unroll
        for (int nt = 0; nt < 8; nt++) {
          const int col = nt * 16 + l16;
          const float gg = p.g[col], bb = p.be[col];
#pragma unroll
          for (int r = 0; r < 4; r++)
            p.msg[(size_t)(e0 + lgr * 4 + r) * 256 + col] =
                f2bf(latS[nt][r] + acc[nt][r] * gg + bb);
        }
      }
    }
  }
}

// ======================= ee kernel (edge encoder MLP) =======================
struct ParamsEE {
  const float* dx; const float* attr;
  const float* b1; const float* b2; const float* g; const float* be;
  const unsigned short* wt;
  unsigned short* msg;   // cols 128..255 = edge_latent
  int ntiles;
};

__global__ __launch_bounds__(256) void ee_kernel(ParamsEE p) {
  __shared__ unsigned short lds[30720];
  const int tid = threadIdx.x;
  const int wave = tid >> 6, lane = tid & 63;
  const int l16 = lane & 15, lgr = lane >> 4;
#pragma unroll
  for (int i = tid * 8; i < 20480; i += 2048)
    *(u16x8*)(lds + i) = *(const u16x8*)(p.wt + WT_EE1 + i);
  const unsigned short* W1 = lds;
  const unsigned short* W2 = lds + 4096;
  unsigned short* h1 = lds + 20480 + wave * 2560;
  unsigned short* feat = h1 + 2048;
  __syncthreads();
  // persistent zeros cols 4..31
#pragma unroll
  for (int j = 0; j < 7; j++) feat[swz32(l16, 4 + lgr * 7 + j)] = 0;
  const fx4 z4 = {0.f, 0.f, 0.f, 0.f};

  for (int t = blockIdx.x; t < p.ntiles; t += gridDim.x) {
    const int e0 = t * 64 + wave * 16;
    const size_t e = (size_t)(e0 + l16);
    if (lgr == 0) {
      float d0 = p.dx[3 * e], d1 = p.dx[3 * e + 1], d2 = p.dx[3 * e + 2];
      feat[swz32(l16, 0)] = f2bf(sqrtf(d0 * d0 + d1 * d1 + d2 * d2));
    } else {
      feat[swz32(l16, lgr)] = f2bf(p.attr[3 * e + (lgr - 1)]);
    }
    fx4 acc[8];
#pragma unroll
    for (int b = 0; b < 8; b++) acc[b] = z4;
    gemm_lds<32, 1>(feat, W1, acc, l16, lgr);
    relu_store(acc, p.b1, h1, l16, lgr);
#pragma unroll
    for (int b = 0; b < 8; b++) acc[b] = z4;
    gemm_lds<128, 4>(h1, W2, acc, l16, lgr);
    ln_rows(acc, p.b2, l16);
#pragma unroll
    for (int nt = 0; nt < 8; nt++) {
      const int col = nt * 16 + l16;
      const float gg = p.g[col], bb = p.be[col];
#pragma unroll
      for (int r = 0; r < 4; r++)
        p.msg[(size_t)(e0 + lgr * 4 + r) * 256 + 128 + col] =
            f2bf(acc[nt][r] * gg + bb);
    }
  }
}

// ======================= ie kernel (interaction MLP, final) =======================
struct ParamsIE {
  const int* eidx;
  const float* nl;
  const float* b1; const float* b2; const float* g; const float* be;
  const unsigned short* wt;
  unsigned short* msg;   // aliases out!
  float* out;
  int E; int ntiles;
};

__global__ __launch_bounds__(256) void ie_kernel(ParamsIE p) {
  extern __shared__ unsigned short dyn[];  // WA|WB|WC|W2 = 65536 ush, + 4x2048 h1
  const int tid = threadIdx.x;
  const int wave = tid >> 6, lane = tid & 63;
  const int l16 = lane & 15, lgr = lane >> 4;
#pragma unroll
  for (int i = tid * 8; i < 65536; i += 2048)
    *(u16x8*)(dyn + i) = *(const u16x8*)(p.wt + WT_A + i);
  const unsigned short* WA = dyn;
  const unsigned short* WB = dyn + 16384;
  const unsigned short* WC = dyn + 32768;
  const unsigned short* W2 = dyn + 49152;
  unsigned short* h1 = dyn + 65536 + wave * 2048;
  __syncthreads();
  const fx4 z4 = {0.f, 0.f, 0.f, 0.f};

  for (int t = blockIdx.x; t < p.ntiles; t += gridDim.x) {
    const int e0 = t * 64 + wave * 16;
    const size_t e = (size_t)(e0 + l16);
    const int sidx = p.eidx[e];
    const int ridx = p.eidx[(size_t)p.E + e];
    const unsigned short* mrow = p.msg + e * 256;
    const float* ns = p.nl + (size_t)sidx * 128;
    const float* nr = p.nl + (size_t)ridx * 128;
    fx4 acc[8];
#pragma unroll
    for (int b = 0; b < 8; b++) acc[b] = z4;
    // node chunks first (longest-latency gathers issue early)
#pragma unroll
    for (int c = 0; c < 4; c++) {
      const int k0 = c * 32 + lgr * 8;
      fx4 a0 = *(const fx4*)(ns + k0), a1 = *(const fx4*)(ns + k0 + 4);
      fx4 b0 = *(const fx4*)(nr + k0), b1 = *(const fx4*)(nr + k0 + 4);
      u16x8 af;
#pragma unroll
      for (int j = 0; j < 4; j++) { af[j] = f2bf(a0[j] + b0[j]); af[4 + j] = f2bf(a1[j] + b1[j]); }
#pragma unroll
      for (int nt = 0; nt < 8; nt++) {
        const int n = nt * 16 + l16;
        u16x8 bf = *(const u16x8*)(WB + swz128(n, k0));
        acc[nt] = mfma16(af, bf, acc[nt]);
      }
    }
    // sr chunks
#pragma unroll
    for (int c = 0; c < 4; c++) {
      const int k0 = c * 32 + lgr * 8;
      u16x8 af = *(const u16x8*)(mrow + k0);
#pragma unroll
      for (int nt = 0; nt < 8; nt++) {
        const int n = nt * 16 + l16;
        u16x8 bf = *(const u16x8*)(WA + swz128(n, k0));
        acc[nt] = mfma16(af, bf, acc[nt]);
      }
    }
    // el chunks
#pragma unroll
    for (int c = 0; c < 4; c++) {
      const int k0 = c * 32 + lgr * 8;
      u16x8 af = *(const u16x8*)(mrow + 128 + k0);
#pragma unroll
      for (int nt = 0; nt < 8; nt++) {
        const int n = nt * 16 + l16;
        u16x8 bf = *(const u16x8*)(WC + swz128(n, k0));
        acc[nt] = mfma16(af, bf, acc[nt]);
      }
    }
    relu_store(acc, p.b1, h1, l16, lgr);
#pragma unroll
    for (int b = 0; b < 8; b++) acc[b] = z4;
    gemm_lds<128, 4>(h1, W2, acc, l16, lgr);
    ln_rows(acc, p.b2, l16);
#pragma unroll
    for (int nt = 0; nt < 8; nt++) {
      const int col = nt * 16 + l16;
      const float gg = p.g[col], bb = p.be[col];
#pragma unroll
      for (int r = 0; r < 4; r++)
        p.out[(size_t)(e0 + lgr * 4 + r) * 128 + col] = acc[nt][r] * gg + bb;
    }
  }
}

extern "C" void kernel_launch(void* const* d_in, const int* in_sizes, int n_in,
                              void* d_out, int out_size, void* d_ws, size_t ws_size,
                              hipStream_t stream) {
  (void)n_in; (void)out_size;
  const int E = in_sizes[1] / 3;  // edge_dx_ is [E,3]
  const int ntiles = E / 64;
  unsigned short* wt = reinterpret_cast<unsigned short*>(d_ws);
  if (ws_size < (size_t)WT_TOTAL * sizeof(unsigned short)) return;

  prep_weights<<<(WT_TOTAL + 255) / 256, 256, 0, stream>>>(
      (const float*)d_in[19], (const float*)d_in[21],
      (const float*)d_in[25], (const float*)d_in[27],
      (const float*)d_in[31], (const float*)d_in[33], wt);

  unsigned short* msg = (unsigned short*)d_out;  // [E][256] bf16 staging inside d_out

  ParamsFE pf;
  for (int i = 0; i < 3; i++) pf.basis[i] = (const float*)d_in[3 + i];
  for (int k = 0; k < 6; k++) { pf.sv[k] = (const float*)d_in[6 + k]; pf.rv[k] = (const float*)d_in[12 + k]; }
  pf.b1 = (const float*)d_in[20]; pf.b2 = (const float*)d_in[22];
  pf.g  = (const float*)d_in[23]; pf.be = (const float*)d_in[24];
  pf.wt = wt; pf.msg = msg; pf.ntiles = ntiles;
  fe_kernel<<<1024, 256, 0, stream>>>(pf);

  ParamsEE pe;
  pe.dx = (const float*)d_in[1]; pe.attr = (const float*)d_in[2];
  pe.b1 = (const float*)d_in[26]; pe.b2 = (const float*)d_in[28];
  pe.g  = (const float*)d_in[29]; pe.be = (const float*)d_in[30];
  pe.wt = wt; pe.msg = msg; pe.ntiles = ntiles;
  ee_kernel<<<512, 256, 0, stream>>>(pe);

  ParamsIE pi;
  pi.eidx = (const int*)d_in[0];
  pi.nl = (const float*)d_in[18];
  pi.b1 = (const float*)d_in[32]; pi.b2 = (const float*)d_in[34];
  pi.g  = (const float*)d_in[35]; pi.be = (const float*)d_in[36];
  pi.wt = wt; pi.msg = msg; pi.out = (float*)d_out;
  pi.E = E; pi.ntiles = ntiles;
  static_assert(sizeof(unsigned short) == 2, "");
  hipFuncSetAttribute((const void*)ie_kernel,
                      hipFuncAttributeMaxDynamicSharedMemorySize, 147456);
  ie_kernel<<<256, 256, 147456, stream>>>(pi);
}